// Round 2
// baseline (6020.814 us; speedup 1.0000x reference)
//
#include <hip/hip_runtime.h>
#include <stdint.h>

#define NEGV   (-1000000000.0f)
#define CONF   0.05f
#define IOUT   0.15f
#define MAXSEL 550
#define CAP    32768
#define M      2048
#define WORDS  32          // M/64
#define NCHUNK 16          // CAP/M

__device__ __forceinline__ float areaf(float4 b) {
    return __fmul_rn(fmaxf(__fsub_rn(b.z, b.x), 0.0f), fmaxf(__fsub_rn(b.w, b.y), 0.0f));
}

// iou(a, b) > 0.15 with union = areaA + areaB - inter, bit-exact vs the JAX f32 sequence.
__device__ __forceinline__ bool iou_gt2(float4 a, float aA, float4 b, float aB) {
    float ltx = fmaxf(a.x, b.x), lty = fmaxf(a.y, b.y);
    float rbx = fminf(a.z, b.z), rby = fminf(a.w, b.w);
    float wx = fmaxf(__fsub_rn(rbx, ltx), 0.0f);
    float wy = fmaxf(__fsub_rn(rby, lty), 0.0f);
    float inter = __fmul_rn(wx, wy);
    float uni = __fsub_rn(__fadd_rn(aA, aB), inter);
    return __fdiv_rn(inter, fmaxf(uni, 1e-8f)) > IOUT;
}

// init: pad keys, zero per-(b,c) state
__global__ void k_init(unsigned long long* __restrict__ keys, unsigned int* __restrict__ selcnt,
                       unsigned int* __restrict__ g_done, int NBC) {
    int t = blockIdx.x * 256 + threadIdx.x;
    keys[t] = ~0ull;
    if (t < NBC) { selcnt[t] = 0; g_done[t] = 0; }
}

__global__ void k_decode(const float* __restrict__ pred, float4* __restrict__ boxes, int BN) {
    int t = blockIdx.x * 256 + threadIdx.x;
    if (t >= BN) return;
    const float* p = pred + (size_t)t * 6;
    float cx = p[0], cy = p[1], w = p[2], h = p[3];
    float hw = __fmul_rn(w, 0.5f), hh = __fmul_rn(h, 0.5f);
    float4 b;
    b.x = __fsub_rn(cx, hw);
    b.y = __fsub_rn(cy, hh);
    b.z = __fadd_rn(cx, hw);
    b.w = __fadd_rn(cy, hh);
    boxes[t] = b;
}

// parallel compaction: count per 256-tile
__global__ __launch_bounds__(256) void k_cnt(const float* __restrict__ pred,
                                             unsigned int* __restrict__ tilecnt,
                                             int Nn, int Cc, int TIL) {
    int bt = blockIdx.x;
    int tile = bt % TIL, bc = bt / TIL;
    int b = bc / Cc, c = bc % Cc;
    int n = tile * 256 + threadIdx.x;
    bool p = false;
    if (n < Nn) {
        float lg = pred[((size_t)b * Nn + n) * 6 + 4 + c];
        float sc = __fdiv_rn(1.0f, __fadd_rn(1.0f, expf(-lg)));
        p = sc > CONF;
    }
    unsigned long long m = __ballot(p);
    __shared__ unsigned int wsum[4];
    if ((threadIdx.x & 63) == 0) wsum[threadIdx.x >> 6] = (unsigned)__popcll(m);
    __syncthreads();
    if (threadIdx.x == 0) tilecnt[bc * TIL + tile] = wsum[0] + wsum[1] + wsum[2] + wsum[3];
}

__global__ void k_scan(const unsigned int* __restrict__ tilecnt, unsigned int* __restrict__ tilebase,
                       unsigned int* __restrict__ cnt, int TIL, int NBC) {
    int bc = threadIdx.x;
    if (bc < NBC) {
        unsigned run = 0;
        for (int t = 0; t < TIL; ++t) { tilebase[bc * TIL + t] = run; run += tilecnt[bc * TIL + t]; }
        cnt[bc] = run < CAP ? run : CAP;
    }
}

__global__ __launch_bounds__(256) void k_write(const float* __restrict__ pred,
                                               const unsigned int* __restrict__ tilebase,
                                               unsigned long long* __restrict__ keys,
                                               int Nn, int Cc, int TIL) {
    int bt = blockIdx.x;
    int tile = bt % TIL, bc = bt / TIL;
    int b = bc / Cc, c = bc % Cc;
    int n = tile * 256 + threadIdx.x;
    bool p = false;
    float sc = 0.f;
    if (n < Nn) {
        float lg = pred[((size_t)b * Nn + n) * 6 + 4 + c];
        sc = __fdiv_rn(1.0f, __fadd_rn(1.0f, expf(-lg)));
        p = sc > CONF;
    }
    unsigned long long m = __ballot(p);
    __shared__ unsigned int wbase[4];
    int wid = threadIdx.x >> 6, lane = threadIdx.x & 63;
    if (lane == 0) wbase[wid] = (unsigned)__popcll(m);
    __syncthreads();
    if (threadIdx.x == 0) {
        unsigned run = 0;
        for (int i = 0; i < 4; ++i) { unsigned t2 = wbase[i]; wbase[i] = run; run += t2; }
    }
    __syncthreads();
    if (p) {
        unsigned pos = tilebase[bc * TIL + tile] + wbase[wid] +
                       (unsigned)__popcll(m & ((1ull << lane) - 1ull));
        if (pos < CAP)
            keys[(size_t)bc * CAP + pos] =
                (((unsigned long long)(~__float_as_uint(sc))) << 32) | (unsigned)n;
    }
}

// bitonic: local full sort of 4096-key tiles in LDS
__global__ __launch_bounds__(1024) void k_sort_local(unsigned long long* __restrict__ keys) {
    __shared__ unsigned long long sk[4096];
    unsigned long long* a = keys + (size_t)blockIdx.x * 4096;
    int lbase = (blockIdx.x & 7) * 4096;   // tile base within this bc's CAP segment
    for (int i = threadIdx.x; i < 4096; i += 1024) sk[i] = a[i];
    __syncthreads();
    for (int k = 2; k <= 4096; k <<= 1) {
        for (int j = k >> 1; j > 0; j >>= 1) {
            for (int idx = threadIdx.x; idx < 2048; idx += 1024) {
                int i = ((idx & ~(j - 1)) << 1) | (idx & (j - 1));
                int p = i | j;
                bool up = (((lbase + i) & k) == 0);
                unsigned long long x = sk[i], y = sk[p];
                if ((x > y) == up) { sk[i] = y; sk[p] = x; }
            }
            __syncthreads();
        }
    }
    for (int i = threadIdx.x; i < 4096; i += 1024) a[i] = sk[i];
}

// bitonic: one global pass (j >= 4096)
__global__ __launch_bounds__(1024) void k_sort_global(unsigned long long* __restrict__ keys, int j, int k) {
    int idx = blockIdx.x * 1024 + threadIdx.x;  // pair index over all bc
    int bc = idx >> 14;                          // 16384 pairs per bc
    int lp = idx & 16383;
    int i = ((lp & ~(j - 1)) << 1) | (lp & (j - 1));
    bool up = ((i & k) == 0);                    // local index for direction
    unsigned long long* a = keys + (size_t)bc * CAP;
    unsigned long long x = a[i], y = a[i | j];
    if ((x > y) == up) { a[i] = y; a[i | j] = x; }
}

// bitonic: remaining j<=2048 stages of merge step k, in LDS per tile
__global__ __launch_bounds__(1024) void k_sort_mergelds(unsigned long long* __restrict__ keys, int k) {
    __shared__ unsigned long long sk[4096];
    unsigned long long* a = keys + (size_t)blockIdx.x * 4096;
    int lbase = (blockIdx.x & 7) * 4096;
    bool up = ((lbase & k) == 0);                // constant per tile (k >= 8192)
    for (int i = threadIdx.x; i < 4096; i += 1024) sk[i] = a[i];
    __syncthreads();
    for (int j = 2048; j > 0; j >>= 1) {
        for (int idx = threadIdx.x; idx < 2048; idx += 1024) {
            int i = ((idx & ~(j - 1)) << 1) | (idx & (j - 1));
            int p = i | j;
            unsigned long long x = sk[i], y = sk[p];
            if ((x > y) == up) { sk[i] = y; sk[p] = x; }
        }
        __syncthreads();
    }
    for (int i = threadIdx.x; i < 4096; i += 1024) a[i] = sk[i];
}

// NMS phase A: per chunk, vs-selected aliveness + pairwise suppression rows (parallel)
__global__ __launch_bounds__(256) void k_mask(const unsigned long long* __restrict__ keys,
                                              const unsigned int* __restrict__ cnt,
                                              const float4* __restrict__ boxes,
                                              const float4* __restrict__ selbox,
                                              const unsigned int* __restrict__ selcnt,
                                              const unsigned int* __restrict__ g_done,
                                              unsigned long long* __restrict__ masks,
                                              unsigned long long* __restrict__ removed0,
                                              int Nn, int Cc, int t) {
    int bc = blockIdx.x >> 3;
    int rb = blockIdx.x & 7;
    if (g_done[bc]) return;
    int b = bc / Cc;
    int start = t * M;
    int cv = (int)cnt[bc];
    __shared__ float4 chB[M];
    __shared__ float  chA[M];
    __shared__ float4 seB[MAXSEL];
    __shared__ float  seA[MAXSEL];
    int S0 = (int)selcnt[bc];
    const unsigned long long* kk = keys + (size_t)bc * CAP;
    for (int r = threadIdx.x; r < M; r += 256) {
        int g = start + r;
        float4 bx = make_float4(0.f, 0.f, 0.f, 0.f);
        if (g < cv) {
            unsigned long long key = kk[g];
            unsigned n = (unsigned)key;
            bx = boxes[(size_t)b * Nn + n];
        }
        chB[r] = bx;
        chA[r] = areaf(bx);
    }
    for (int s = threadIdx.x; s < S0; s += 256) {
        float4 sb = selbox[bc * MAXSEL + s];
        seB[s] = sb;
        seA[s] = areaf(sb);
    }
    __syncthreads();
    int il = rb * 256 + threadIdx.x;
    int g = start + il;
    bool alive = g < cv;
    float4 bx = chB[il];
    float aA = chA[il];
    if (alive) {
        for (int s = 0; s < S0; ++s) {
            if (iou_gt2(seB[s], seA[s], bx, aA)) { alive = false; break; }
        }
    }
    unsigned long long mav = __ballot(alive);
    if ((threadIdx.x & 63) == 0) removed0[bc * WORDS + (il >> 6)] = ~mav;
    if (!alive) return;
    int climit = cv - start; if (climit > M) climit = M;
    unsigned long long* row = masks + (size_t)bc * WORDS * M;
    for (int w = il >> 6; w < WORDS; ++w) {
        unsigned long long bits = 0;
        int cb = w << 6;
        int jend = climit - cb; if (jend > 64) jend = 64;
        int j0 = (cb > il) ? 0 : (il + 1 - cb);
        for (int j = j0; j < jend; ++j) {
            int col = cb + j;
            if (iou_gt2(bx, aA, chB[col], chA[col])) bits |= (1ull << j);
        }
        row[(size_t)w * M + il] = bits;
    }
}

// NMS phase B: serial greedy sweep over the chunk's bitmask (one wave per (b,c))
__global__ __launch_bounds__(64) void k_sweep(const unsigned long long* __restrict__ keys,
                                              const unsigned int* __restrict__ cnt,
                                              const float4* __restrict__ boxes,
                                              const unsigned long long* __restrict__ masks,
                                              const unsigned long long* __restrict__ removed0,
                                              unsigned int* __restrict__ sel_n,
                                              float* __restrict__ sel_s,
                                              float4* __restrict__ selbox,
                                              unsigned int* __restrict__ selcnt,
                                              unsigned int* __restrict__ g_done,
                                              int Nn, int Cc, int t) {
    int bc = blockIdx.x;
    if (g_done[bc]) return;
    int lane = threadIdx.x;
    int start = t * M;
    int cv = (int)cnt[bc];
    int b = bc / Cc;
    if (start >= cv) { if (lane == 0) g_done[bc] = 1; return; }
    unsigned long long rem = (lane < WORDS) ? removed0[bc * WORDS + lane] : ~0ull;
    int sel = (int)selcnt[bc];
    const unsigned long long* kk = keys + (size_t)bc * CAP + start;
    const unsigned long long* mk = masks + (size_t)bc * WORDS * M;
    while (sel < MAXSEL) {
        bool av = (lane < WORDS) && (rem != ~0ull);
        unsigned long long mm = __ballot(av);
        if (mm == 0) break;
        int w0 = __builtin_ctzll(mm);
        unsigned long long word = __shfl((unsigned long long)(~rem), w0);
        int kz = __builtin_ctzll(word);
        int i = (w0 << 6) + kz;
        unsigned long long key = kk[i];
        if (lane < WORDS) rem |= mk[(size_t)lane * M + i];
        if (lane == w0) rem |= (1ull << kz);
        if (lane == 0) {
            unsigned n = (unsigned)key;
            sel_n[bc * MAXSEL + sel] = n;
            sel_s[bc * MAXSEL + sel] = __uint_as_float(~(unsigned)(key >> 32));
            selbox[bc * MAXSEL + sel] = boxes[(size_t)b * Nn + n];
        }
        ++sel;
    }
    if (lane == 0) {
        selcnt[bc] = (unsigned)sel;
        if (sel >= MAXSEL || start + M >= cv) g_done[bc] = 1;
    }
}

// final: per-batch full sort of C*550 entries (== top_k) + output write
__global__ __launch_bounds__(1024) void k_final(const unsigned int* __restrict__ selcnt,
                                                const unsigned int* __restrict__ sel_n,
                                                const float* __restrict__ sel_s,
                                                const float4* __restrict__ boxes,
                                                float* __restrict__ out,
                                                int Nn, int Cc, int Bb) {
    int b = blockIdx.x, tid = threadIdx.x;
    const int TOT = MAXSEL * 2;   // 1100
    __shared__ unsigned long long sk[2048];
    unsigned c0 = selcnt[b * Cc + 0];
    unsigned c1 = selcnt[b * Cc + 1];
    for (int t = tid; t < 2048; t += 1024) {
        unsigned long long key;
        if (t < TOT) {
            int c = t / MAXSEL, k2 = t % MAXSEL;
            unsigned cc = (c == 0) ? c0 : c1;
            float sc = (k2 < (int)cc) ? sel_s[(size_t)(b * Cc + c) * MAXSEL + k2] : NEGV;
            unsigned u = __float_as_uint(sc);
            unsigned ord = (u & 0x80000000u) ? ~u : (u | 0x80000000u);
            key = (((unsigned long long)(~ord)) << 32) | (unsigned)t;
        } else {
            key = ~0ull;
        }
        sk[t] = key;
    }
    __syncthreads();
    for (int k = 2; k <= 2048; k <<= 1) {
        for (int j = k >> 1; j > 0; j >>= 1) {
            int idx = tid;
            int i = ((idx & ~(j - 1)) << 1) | (idx & (j - 1));
            int p = i | j;
            bool up = ((i & k) == 0);
            unsigned long long x = sk[i], y = sk[p];
            if ((x > y) == up) { sk[i] = y; sk[p] = x; }
            __syncthreads();
        }
    }
    int off_scores = Bb * TOT * 4;
    int off_classes = off_scores + Bb * TOT;
    int off_valid = off_classes + Bb * TOT;
    for (int r = tid; r < TOT; r += 1024) {
        unsigned long long key = sk[r];
        unsigned flat = (unsigned)(key & 0xffffffffull);
        unsigned hi = (unsigned)(key >> 32);
        unsigned ord = ~hi;
        float sc = (ord & 0x80000000u) ? __uint_as_float(ord & 0x7fffffffu)
                                       : __uint_as_float(~ord);
        bool valid = sc > -5.0e8f;
        int c = (int)(flat / MAXSEL), k2 = (int)(flat % MAXSEL);
        float4 bxv = make_float4(0.f, 0.f, 0.f, 0.f);
        float so = 0.f, co = 0.f;
        if (valid) {
            unsigned n = sel_n[(size_t)(b * Cc + c) * MAXSEL + k2];
            bxv = boxes[(size_t)b * Nn + n];
            so = sc;
            co = (float)c;
        }
        ((float4*)out)[b * TOT + r] = bxv;
        out[off_scores + b * TOT + r] = so;
        out[off_classes + b * TOT + r] = co;
    }
    if (tid == 0) out[off_valid + b] = (float)(c0 + c1);
}

extern "C" void kernel_launch(void* const* d_in, const int* in_sizes, int n_in,
                              void* d_out, int out_size, void* d_ws, size_t ws_size,
                              hipStream_t stream) {
    const float* pred = (const float*)d_in[1];
    float* out = (float*)d_out;
    int Bb = out_size / 6601;            // 4
    int Nn = in_sizes[1] / (6 * Bb);     // 49104
    const int Cc = 2;
    if (Bb <= 0 || Nn <= 0) return;
    int NBC = Bb * Cc;                   // 8
    int TIL = (Nn + 255) / 256;          // 192

    char* ws = (char*)d_ws;
    size_t off = 0;
    auto alloc = [&](size_t bytes) { void* p = ws + off; off = (off + bytes + 255) & ~(size_t)255; return p; };
    float4* boxes               = (float4*)alloc((size_t)Bb * Nn * 16);
    unsigned long long* keys    = (unsigned long long*)alloc((size_t)NBC * CAP * 8);
    unsigned int* cnt           = (unsigned int*)alloc(NBC * 4);
    unsigned int* tilecnt       = (unsigned int*)alloc((size_t)NBC * TIL * 4);
    unsigned int* tilebase      = (unsigned int*)alloc((size_t)NBC * TIL * 4);
    unsigned int* sel_n         = (unsigned int*)alloc((size_t)NBC * MAXSEL * 4);
    float* sel_s                = (float*)alloc((size_t)NBC * MAXSEL * 4);
    float4* selbox              = (float4*)alloc((size_t)NBC * MAXSEL * 16);
    unsigned int* selcnt        = (unsigned int*)alloc(NBC * 4);
    unsigned int* g_done        = (unsigned int*)alloc(NBC * 4);
    unsigned long long* removed0= (unsigned long long*)alloc((size_t)NBC * WORDS * 8);
    unsigned long long* masks   = (unsigned long long*)alloc((size_t)NBC * WORDS * M * 8);
    if (off > ws_size) return;  // workspace too small — fail visibly

    int BN = Bb * Nn;
    k_init<<<NBC * CAP / 256, 256, 0, stream>>>(keys, selcnt, g_done, NBC);
    k_decode<<<(BN + 255) / 256, 256, 0, stream>>>(pred, boxes, BN);
    k_cnt<<<NBC * TIL, 256, 0, stream>>>(pred, tilecnt, Nn, Cc, TIL);
    k_scan<<<1, 64, 0, stream>>>(tilecnt, tilebase, cnt, TIL, NBC);
    k_write<<<NBC * TIL, 256, 0, stream>>>(pred, tilebase, keys, Nn, Cc, TIL);

    int ntiles = NBC * (CAP / 4096);     // 64
    k_sort_local<<<ntiles, 1024, 0, stream>>>(keys);
    for (int k = 8192; k <= CAP; k <<= 1) {
        for (int j = k >> 1; j >= 4096; j >>= 1)
            k_sort_global<<<NBC * (CAP / 2) / 1024, 1024, 0, stream>>>(keys, j, k);
        k_sort_mergelds<<<ntiles, 1024, 0, stream>>>(keys, k);
    }

    for (int t = 0; t < NCHUNK; ++t) {
        k_mask<<<NBC * 8, 256, 0, stream>>>(keys, cnt, boxes, selbox, selcnt, g_done,
                                            masks, removed0, Nn, Cc, t);
        k_sweep<<<NBC, 64, 0, stream>>>(keys, cnt, boxes, masks, removed0,
                                        sel_n, sel_s, selbox, selcnt, g_done, Nn, Cc, t);
    }
    k_final<<<Bb, 1024, 0, stream>>>(selcnt, sel_n, sel_s, boxes, out, Nn, Cc, Bb);
}

// Round 3
// 1919.258 us; speedup vs baseline: 3.1371x; 3.1371x over previous
//
#include <hip/hip_runtime.h>
#include <stdint.h>

#define NEGV   (-1000000000.0f)
#define CONF   0.05f
#define IOUT   0.15f
#define MAXSEL 550
#define CAP    32768
#define WIN    2048
#define SLOTS  2          // WIN / 1024
#define INFIDX 0x7fffffff

__device__ __forceinline__ float areaf(float4 b) {
    return __fmul_rn(fmaxf(__fsub_rn(b.z, b.x), 0.0f), fmaxf(__fsub_rn(b.w, b.y), 0.0f));
}

// iou(a,b) > 0.15, bit-exact vs the JAX f32 sequence (no FMA contraction).
__device__ __forceinline__ bool iou_gt2(float4 a, float aA, float4 b, float aB) {
    float ltx = fmaxf(a.x, b.x), lty = fmaxf(a.y, b.y);
    float rbx = fminf(a.z, b.z), rby = fminf(a.w, b.w);
    float wx = fmaxf(__fsub_rn(rbx, ltx), 0.0f);
    float wy = fmaxf(__fsub_rn(rby, lty), 0.0f);
    float inter = __fmul_rn(wx, wy);
    float uni = __fsub_rn(__fadd_rn(aA, aB), inter);
    return __fdiv_rn(inter, fmaxf(uni, 1e-8f)) > IOUT;
}

__global__ void k_decode(const float* __restrict__ pred, float4* __restrict__ boxes, int BN) {
    int t = blockIdx.x * 256 + threadIdx.x;
    if (t >= BN) return;
    const float* p = pred + (size_t)t * 6;
    float cx = p[0], cy = p[1], w = p[2], h = p[3];
    float hw = __fmul_rn(w, 0.5f), hh = __fmul_rn(h, 0.5f);
    float4 b;
    b.x = __fsub_rn(cx, hw);
    b.y = __fsub_rn(cy, hh);
    b.z = __fadd_rn(cx, hw);
    b.w = __fadd_rn(cy, hh);
    boxes[t] = b;
}

// per (b,c) order-preserving compaction of sigmoid>CONF candidates; pads tail to CAP.
// key = (~score_bits << 32) | n : ascending u64 sort == (score desc, n asc).
__global__ __launch_bounds__(1024) void k_compact(const float* __restrict__ pred,
                                                  unsigned long long* __restrict__ keys,
                                                  unsigned int* __restrict__ cnt,
                                                  int Nn, int Cc) {
    int bc = blockIdx.x;
    int b = bc / Cc, c = bc % Cc;
    int tid = threadIdx.x, lane = tid & 63, wid = tid >> 6;
    __shared__ unsigned int wsum[16];
    __shared__ unsigned int sbase, stot;
    if (tid == 0) sbase = 0;
    __syncthreads();
    unsigned long long* kk = keys + (size_t)bc * CAP;
    for (int tile = 0; tile < Nn; tile += 1024) {
        int n = tile + tid;
        bool p = false;
        float sc = 0.f;
        if (n < Nn) {
            float lg = pred[((size_t)b * Nn + n) * 6 + 4 + c];
            sc = __fdiv_rn(1.0f, __fadd_rn(1.0f, expf(-lg)));
            p = sc > CONF;
        }
        unsigned long long m = __ballot(p);
        if (lane == 0) wsum[wid] = (unsigned)__popcll(m);
        __syncthreads();
        if (tid == 0) {
            unsigned run = 0;
            for (int w2 = 0; w2 < 16; ++w2) { unsigned t2 = wsum[w2]; wsum[w2] = run; run += t2; }
            stot = run;
        }
        __syncthreads();
        if (p) {
            unsigned rank = (unsigned)__popcll(m & ((1ull << lane) - 1ull));
            unsigned pos = sbase + wsum[wid] + rank;
            if (pos < CAP)
                kk[pos] = (((unsigned long long)(~__float_as_uint(sc))) << 32) | (unsigned)n;
        }
        __syncthreads();
        if (tid == 0) sbase += stot;
        __syncthreads();
    }
    unsigned total = sbase;
    unsigned cv = total < CAP ? total : CAP;
    if (tid == 0) cnt[bc] = cv;
    for (unsigned i = cv + tid; i < CAP; i += 1024) kk[i] = ~0ull;
}

// bitonic: local full sort of 4096-key tiles in LDS
__global__ __launch_bounds__(1024) void k_sort_local(unsigned long long* __restrict__ keys) {
    __shared__ unsigned long long sk[4096];
    unsigned long long* a = keys + (size_t)blockIdx.x * 4096;
    int lbase = (blockIdx.x & 7) * 4096;
    for (int i = threadIdx.x; i < 4096; i += 1024) sk[i] = a[i];
    __syncthreads();
    for (int k = 2; k <= 4096; k <<= 1) {
        for (int j = k >> 1; j > 0; j >>= 1) {
            for (int idx = threadIdx.x; idx < 2048; idx += 1024) {
                int i = ((idx & ~(j - 1)) << 1) | (idx & (j - 1));
                int p = i | j;
                bool up = (((lbase + i) & k) == 0);
                unsigned long long x = sk[i], y = sk[p];
                if ((x > y) == up) { sk[i] = y; sk[p] = x; }
            }
            __syncthreads();
        }
    }
    for (int i = threadIdx.x; i < 4096; i += 1024) a[i] = sk[i];
}

// bitonic: one global pass (j >= 4096)
__global__ __launch_bounds__(1024) void k_sort_global(unsigned long long* __restrict__ keys, int j, int k) {
    int idx = blockIdx.x * 1024 + threadIdx.x;
    int bc = idx >> 14;
    int lp = idx & 16383;
    int i = ((lp & ~(j - 1)) << 1) | (lp & (j - 1));
    bool up = ((i & k) == 0);
    unsigned long long* a = keys + (size_t)bc * CAP;
    unsigned long long x = a[i], y = a[i | j];
    if ((x > y) == up) { a[i] = y; a[i | j] = x; }
}

// bitonic: remaining j<=2048 stages of merge step k, in LDS per 4096-tile
__global__ __launch_bounds__(1024) void k_sort_mergelds(unsigned long long* __restrict__ keys, int k) {
    __shared__ unsigned long long sk[4096];
    unsigned long long* a = keys + (size_t)blockIdx.x * 4096;
    int lbase = (blockIdx.x & 7) * 4096;
    bool up = ((lbase & k) == 0);
    for (int i = threadIdx.x; i < 4096; i += 1024) sk[i] = a[i];
    __syncthreads();
    for (int j = 2048; j > 0; j >>= 1) {
        for (int idx = threadIdx.x; idx < 2048; idx += 1024) {
            int i = ((idx & ~(j - 1)) << 1) | (idx & (j - 1));
            int p = i | j;
            unsigned long long x = sk[i], y = sk[p];
            if ((x > y) == up) { sk[i] = y; sk[p] = x; }
        }
        __syncthreads();
    }
    for (int i = threadIdx.x; i < 4096; i += 1024) a[i] = sk[i];
}

// Fused greedy NMS: one block per (b,c); windows of WIN sorted candidates staged in LDS;
// serial greedy chain runs entirely on LDS + registers (2 barriers/step).
__global__ __launch_bounds__(1024) void k_nms_lds(const unsigned long long* __restrict__ keys,
                                                  const unsigned int* __restrict__ cnt,
                                                  const float4* __restrict__ boxes,
                                                  unsigned int* __restrict__ sel_n,
                                                  float* __restrict__ sel_s,
                                                  unsigned int* __restrict__ selcnt,
                                                  int Nn, int Cc) {
    int bc = blockIdx.x, b = bc / Cc;
    int tid = threadIdx.x, lane = tid & 63, wid = tid >> 6;
    __shared__ float4 wbox[WIN];        // 32 KB: window candidate boxes
    __shared__ float4 selb[MAXSEL];     // selected boxes (for refill re-tests)
    __shared__ float  sela[MAXSEL];
    __shared__ int    smin[16];
    __shared__ float4 pub;              // last selected box (published)
    __shared__ int    s_sel;
    if (tid == 0) s_sel = 0;
    int cv = (int)cnt[bc];
    const unsigned long long* kk = keys + (size_t)bc * CAP;

    for (int base = 0; base < cv; base += WIN) {
        __syncthreads();                           // s_sel stable; prev window done
        int S0 = s_sel;
        if (S0 >= MAXSEL) break;
        // ---- refill: stage WIN candidates, test vs already-selected (all LDS) ----
        unsigned long long kreg[SLOTS];
        unsigned amask = 0;
        for (int r = 0; r < SLOTS; ++r) {
            int widx = r * 1024 + tid;
            int g = base + widx;
            bool al = g < cv;
            if (al) {
                kreg[r] = kk[g];
                float4 bx = boxes[(size_t)b * Nn + (unsigned)kreg[r]];
                wbox[widx] = bx;
                float aA = areaf(bx);
                for (int s = 0; s < S0; ++s) {
                    if (iou_gt2(selb[s], sela[s], bx, aA)) { al = false; break; }
                }
            }
            if (al) amask |= (1u << r);
        }
        __syncthreads();                           // wbox ready
        // ---- greedy step loop ----
        bool first = true;
        for (;;) {
            if (!first && amask) {                 // suppress vs published box
                float4 p = pub;
                float pa = areaf(p);
                unsigned m = amask;
                while (m) {
                    int r = __builtin_ctz(m); m &= m - 1;
                    int widx = (r << 10) + tid;
                    float4 bx = wbox[widx];
                    if (iou_gt2(bx, areaf(bx), p, pa)) amask &= ~(1u << r);
                }
            }
            first = false;
            int my = amask ? ((__builtin_ctz(amask) << 10) + tid) : INFIDX;
            for (int off = 32; off; off >>= 1) {
                int o = __shfl_xor(my, off);
                my = o < my ? o : my;
            }
            if (lane == 0) smin[wid] = my;
            __syncthreads();                       // B1
            int gmin = smin[0];
            #pragma unroll
            for (int i2 = 1; i2 < 16; ++i2) gmin = smin[i2] < gmin ? smin[i2] : gmin;
            if (gmin == INFIDX) break;             // window exhausted (uniform)
            if (tid == (gmin & 1023)) {            // owner publishes + records
                int r = gmin >> 10;
                amask &= ~(1u << r);
                float4 bx = wbox[gmin];
                pub = bx;
                int s = s_sel;
                sel_n[bc * MAXSEL + s] = (unsigned)kreg[r];
                sel_s[bc * MAXSEL + s] = __uint_as_float(~(unsigned)(kreg[r] >> 32));
                selb[s] = bx;
                sela[s] = areaf(bx);
                s_sel = s + 1;
            }
            __syncthreads();                       // B2
            if (s_sel >= MAXSEL) break;            // uniform
        }
    }
    __syncthreads();
    if (tid == 0) selcnt[bc] = (unsigned)s_sel;
}

// final: per-batch full sort of C*550 entries (== top_k) + output write
__global__ __launch_bounds__(1024) void k_final(const unsigned int* __restrict__ selcnt,
                                                const unsigned int* __restrict__ sel_n,
                                                const float* __restrict__ sel_s,
                                                const float4* __restrict__ boxes,
                                                float* __restrict__ out,
                                                int Nn, int Cc, int Bb) {
    int b = blockIdx.x, tid = threadIdx.x;
    const int TOT = MAXSEL * 2;   // 1100
    __shared__ unsigned long long sk[2048];
    unsigned c0 = selcnt[b * Cc + 0];
    unsigned c1 = selcnt[b * Cc + 1];
    for (int t = tid; t < 2048; t += 1024) {
        unsigned long long key;
        if (t < TOT) {
            int c = t / MAXSEL, k2 = t % MAXSEL;
            unsigned cc = (c == 0) ? c0 : c1;
            float sc = (k2 < (int)cc) ? sel_s[(size_t)(b * Cc + c) * MAXSEL + k2] : NEGV;
            unsigned u = __float_as_uint(sc);
            unsigned ord = (u & 0x80000000u) ? ~u : (u | 0x80000000u);
            key = (((unsigned long long)(~ord)) << 32) | (unsigned)t;
        } else {
            key = ~0ull;
        }
        sk[t] = key;
    }
    __syncthreads();
    for (int k = 2; k <= 2048; k <<= 1) {
        for (int j = k >> 1; j > 0; j >>= 1) {
            int idx = tid;
            int i = ((idx & ~(j - 1)) << 1) | (idx & (j - 1));
            int p = i | j;
            bool up = ((i & k) == 0);
            unsigned long long x = sk[i], y = sk[p];
            if ((x > y) == up) { sk[i] = y; sk[p] = x; }
            __syncthreads();
        }
    }
    int off_scores = Bb * TOT * 4;
    int off_classes = off_scores + Bb * TOT;
    int off_valid = off_classes + Bb * TOT;
    for (int r = tid; r < TOT; r += 1024) {
        unsigned long long key = sk[r];
        unsigned flat = (unsigned)(key & 0xffffffffull);
        unsigned hi = (unsigned)(key >> 32);
        unsigned ord = ~hi;
        float sc = (ord & 0x80000000u) ? __uint_as_float(ord & 0x7fffffffu)
                                       : __uint_as_float(~ord);
        bool valid = sc > -5.0e8f;
        int c = (int)(flat / MAXSEL), k2 = (int)(flat % MAXSEL);
        float4 bxv = make_float4(0.f, 0.f, 0.f, 0.f);
        float so = 0.f, co = 0.f;
        if (valid) {
            unsigned n = sel_n[(size_t)(b * Cc + c) * MAXSEL + k2];
            bxv = boxes[(size_t)b * Nn + n];
            so = sc;
            co = (float)c;
        }
        ((float4*)out)[b * TOT + r] = bxv;
        out[off_scores + b * TOT + r] = so;
        out[off_classes + b * TOT + r] = co;
    }
    if (tid == 0) out[off_valid + b] = (float)(c0 + c1);
}

extern "C" void kernel_launch(void* const* d_in, const int* in_sizes, int n_in,
                              void* d_out, int out_size, void* d_ws, size_t ws_size,
                              hipStream_t stream) {
    const float* pred = (const float*)d_in[1];
    float* out = (float*)d_out;
    int Bb = out_size / 6601;            // 4
    int Nn = in_sizes[1] / (6 * Bb);     // 49104
    const int Cc = 2;
    if (Bb <= 0 || Nn <= 0) return;
    int NBC = Bb * Cc;                   // 8

    char* ws = (char*)d_ws;
    size_t off = 0;
    auto alloc = [&](size_t bytes) { void* p = ws + off; off = (off + bytes + 255) & ~(size_t)255; return p; };
    float4* boxes            = (float4*)alloc((size_t)Bb * Nn * 16);
    unsigned long long* keys = (unsigned long long*)alloc((size_t)NBC * CAP * 8);
    unsigned int* cnt        = (unsigned int*)alloc(NBC * 4);
    unsigned int* sel_n      = (unsigned int*)alloc((size_t)NBC * MAXSEL * 4);
    float* sel_s             = (float*)alloc((size_t)NBC * MAXSEL * 4);
    unsigned int* selcnt     = (unsigned int*)alloc(NBC * 4);
    if (off > ws_size) return;

    int BN = Bb * Nn;
    k_decode<<<(BN + 255) / 256, 256, 0, stream>>>(pred, boxes, BN);
    k_compact<<<NBC, 1024, 0, stream>>>(pred, keys, cnt, Nn, Cc);

    int ntiles = NBC * (CAP / 4096);     // 64
    k_sort_local<<<ntiles, 1024, 0, stream>>>(keys);
    for (int k = 8192; k <= CAP; k <<= 1) {
        for (int j = k >> 1; j >= 4096; j >>= 1)
            k_sort_global<<<NBC * (CAP / 2) / 1024, 1024, 0, stream>>>(keys, j, k);
        k_sort_mergelds<<<ntiles, 1024, 0, stream>>>(keys, k);
    }

    k_nms_lds<<<NBC, 1024, 0, stream>>>(keys, cnt, boxes, sel_n, sel_s, selcnt, Nn, Cc);
    k_final<<<Bb, 1024, 0, stream>>>(selcnt, sel_n, sel_s, boxes, out, Nn, Cc, Bb);
}